// Round 3
// baseline (239.028 us; speedup 1.0000x reference)
//
#include <hip/hip_runtime.h>
#include <math.h>

// Problem constants (from reference setup_inputs)
#define L0      3072
#define BATCH   1024
#define NNEG    512
#define NBLK    256

// -------- workspace layout (float indices into d_ws) --------
// X0 : bf16[393216]            (feat @ w_self_0, bf16)
// Y0 : bf16[393216]            = X0 + 393216 elems
// (H eliminated — layer-1 input tile lives in LDS only)
// R  : float @ 1966080 (3072*256)  layer-1 output, normalized
// spPos @ 2752512, spNeg @ 2752513, rank @ 2752514 (1024 ints),
// done @ rank+1024, bar[3] @ done+1, NT @ 2753544 (float[256][512])

__device__ __forceinline__ float bf2f(unsigned short u) {
  return __uint_as_float(((unsigned)u) << 16);
}
__device__ __forceinline__ unsigned short f2bf(float v) {
  unsigned x = __float_as_uint(v);                 // f32 -> bf16 RNE
  return (unsigned short)((x + 0x7fff + ((x >> 16) & 1)) >> 16);
}
__device__ __forceinline__ float softplusf(float x) {
  return fmaxf(x, 0.f) + log1pf(expf(-fabsf(x)));
}

// Device-scope grid barrier. Safe: grid=256 blocks, 512 thr, ~34 KB LDS ->
// occupancy >= 2 blocks/CU on 256 CUs = capacity >= 512 >= grid, so all
// blocks are co-resident (no forward-progress hazard). Fence machinery
// (threadfence + agent-scope atomics) is the SAME pattern the done-counter
// finalize validated cross-XCD on this harness in prior rounds.
__device__ __forceinline__ void gbar(int* ctr) {
  __syncthreads();
  if (threadIdx.x == 0) {
    __threadfence();
    __hip_atomic_fetch_add(ctr, 1, __ATOMIC_ACQ_REL, __HIP_MEMORY_SCOPE_AGENT);
    while (__hip_atomic_load(ctr, __ATOMIC_ACQUIRE,
                             __HIP_MEMORY_SCOPE_AGENT) < NBLK)
      __builtin_amdgcn_s_sleep(1);
  }
  __syncthreads();
}

struct D2S {                        // phase D2 (neg) shared state
  float SP[32 * 260];               // rows [0,16) src, [16,32) pos
  float affL[16];
  int   cntL[16];
  float wsum[8];
  int   lastDone;
};
union SMU {
  float AT[12 * 512];               // phase A: 12x128 feat tile; B/C: 12x512 H tile
  D2S   d2;
};

// Zeroes spPos, spNeg, rank[1024], done, bar[3] (kernel boundary orders this
// before k_fused's first barrier arrival).
__global__ __launch_bounds__(256) void k_zero(float* z) {
  const int t = threadIdx.x;
  for (int i = t; i < 1030; i += 256) z[i] = 0.f;
}

__global__ __launch_bounds__(512) void k_fused(
    const float* __restrict__ feat, const int* __restrict__ src_idx,
    const int* __restrict__ pos_idx, const int* __restrict__ neg_idx,
    const int* __restrict__ nb0, const int* __restrict__ nb1,
    const int* __restrict__ nb2,
    const float* __restrict__ ws0, const float* __restrict__ wn0,
    const float* __restrict__ ws1, const float* __restrict__ wn1,
    unsigned short* __restrict__ X0, unsigned short* __restrict__ Y0,
    float* __restrict__ R, float* __restrict__ NT,
    float* __restrict__ spPos, float* __restrict__ spNeg,
    int* __restrict__ rank, int* __restrict__ done, int* __restrict__ bar,
    float* __restrict__ out) {
  __shared__ SMU sm;
  __shared__ float rs2[8][3];
  const int t = threadIdx.x;
  const int bid = blockIdx.x;
  const int wave = t >> 6, lane = t & 63;
  const int base = bid * 12;                 // this block's 12 node rows

  // ================= Phase A: X0 = bf16(feat@ws0), Y0 = bf16(feat@wn0) ====
  // 12 rows/block; 8 waves = 2 halves x 4 rowgroups; thread = 3 rows x 2 cols.
  // fmaf chain (d asc, i2 inner) identical to the verified k_mm.
  {
    const float4* __restrict__ src = (const float4*)(feat + base * 128);
    float4* __restrict__ dst = (float4*)sm.AT;
    for (int idx = t; idx < 384; idx += 512) dst[idx] = src[idx];
    __syncthreads();
    const int half = wave >> 2;
    const int rg = (wave & 3) * 3;
    const float* __restrict__ W = (half ? wn0 : ws0) + lane;
    const float* __restrict__ A0 = sm.AT + rg * 128;
    float acc[3][2] = {{0.f, 0.f}, {0.f, 0.f}, {0.f, 0.f}};
#pragma unroll 4
    for (int d = 0; d < 128; d += 4) {
      float4 a[3];
#pragma unroll
      for (int r = 0; r < 3; ++r) a[r] = *(const float4*)&A0[r * 128 + d];
      float w0[4], w1[4];
#pragma unroll
      for (int i2 = 0; i2 < 4; ++i2) {
        w0[i2] = W[(d + i2) * 128];
        w1[i2] = W[(d + i2) * 128 + 64];
      }
#pragma unroll
      for (int i2 = 0; i2 < 4; ++i2)
#pragma unroll
        for (int r = 0; r < 3; ++r) {
          const float av = ((const float*)&a[r])[i2];
          acc[r][0] = fmaf(av, w0[i2], acc[r][0]);
          acc[r][1] = fmaf(av, w1[i2], acc[r][1]);
        }
    }
    unsigned short* __restrict__ O = half ? Y0 : X0;
#pragma unroll
    for (int r = 0; r < 3; ++r) {
      O[(base + rg + r) * 128 + lane] = f2bf(acc[r][0]);
      O[(base + rg + r) * 128 + lane + 64] = f2bf(acc[r][1]);
    }
  }
  gbar(&bar[0]);                     // X0/Y0 complete device-wide

  // ================= Phase B: aggregate, register-only, H-tile -> LDS =====
  // wave handles a full node i (10 hop rows serially, accum in registers).
  // Lane (sub=lane>>4, c8=lane&15): c8 = 8-col slot, sub = 4-way partition of
  // the 25 nb2 rows (redundant B/C accumulation across subs is broadcast-free).
  // Output row written straight into sm.AT[wi*512 + sub*128 + c8*8] — the H
  // global round-trip is eliminated (phase C consumes the same block's rows).
  {
    const int c8 = lane & 15, sub = lane >> 4;
    for (int rep = 0; rep < 2; ++rep) {
      const int wi = wave + rep * 8;
      if (wi < 12) {
        const int i = base + wi;
        const int n0 = nb0[i];
        float Ba[8], Ca[8], Da[8];
#pragma unroll
        for (int e = 0; e < 8; ++e) { Ba[e] = 0.f; Ca[e] = 0.f; Da[e] = 0.f; }
#pragma unroll 2
        for (int j = 0; j < 10; ++j) {
          const int r = i * 10 + j;
          int myidx = 0;
          if (lane < 25) myidx = nb2[r * 25 + lane];
          else if (lane == 25) myidx = nb1[r];
          float d8[8];
#pragma unroll
          for (int e = 0; e < 8; ++e) d8[e] = 0.f;
#pragma unroll
          for (int m = 0; m < 7; ++m) {
            const int k = sub + 4 * m;
            const int ridx = __shfl(myidx, k, 64);
            if (k < 25) {
              const float4 raw = *(const float4*)(Y0 + ridx * 128 + c8 * 8);
              const unsigned short* u = (const unsigned short*)&raw;
#pragma unroll
              for (int e = 0; e < 8; ++e) d8[e] += bf2f(u[e]);
            }
          }
#pragma unroll
          for (int e = 0; e < 8; ++e) d8[e] += __shfl_xor(d8[e], 16, 64);
#pragma unroll
          for (int e = 0; e < 8; ++e) d8[e] += __shfl_xor(d8[e], 32, 64);
#pragma unroll
          for (int e = 0; e < 8; ++e) Da[e] += fmaxf(d8[e] * 0.04f, 0.f);
          const int r1 = __shfl(myidx, 25, 64);
          {
            const float4 raw = *(const float4*)(Y0 + r1 * 128 + c8 * 8);
            const unsigned short* u = (const unsigned short*)&raw;
#pragma unroll
            for (int e = 0; e < 8; ++e) Ba[e] += bf2f(u[e]);
          }
          {
            const float4 raw = *(const float4*)(X0 + r1 * 128 + c8 * 8);
            const unsigned short* u = (const unsigned short*)&raw;
#pragma unroll
            for (int e = 0; e < 8; ++e) Ca[e] += fmaxf(bf2f(u[e]), 0.f);
          }
        }
        float v8[8];
        if (sub == 0) {
          const float4 raw = *(const float4*)(X0 + n0 * 128 + c8 * 8);
          const unsigned short* u = (const unsigned short*)&raw;
#pragma unroll
          for (int e = 0; e < 8; ++e) v8[e] = fmaxf(bf2f(u[e]), 0.f);
        } else if (sub == 1) {
#pragma unroll
          for (int e = 0; e < 8; ++e) v8[e] = fmaxf(Ba[e] * 0.1f, 0.f);
        } else if (sub == 2) {
#pragma unroll
          for (int e = 0; e < 8; ++e) v8[e] = Ca[e] * 0.1f;
        } else {
#pragma unroll
          for (int e = 0; e < 8; ++e) v8[e] = Da[e] * 0.1f;
        }
        float* __restrict__ Hp = &sm.AT[wi * 512 + sub * 128 + c8 * 8];
        *(float4*)Hp = make_float4(v8[0], v8[1], v8[2], v8[3]);
        *(float4*)(Hp + 4) = make_float4(v8[4], v8[5], v8[6], v8[7]);
      }
    }
  }
  __syncthreads();                   // H tile (this block's 12 rows) ready

  // ================= Phase C: R = l2norm([H@ws1 | H@wn1]) ================
  {
    const int half = wave >> 2;
    const int rowg = wave & 3;
    const int rg = rowg * 3;
    const float* __restrict__ W = (half ? wn1 : ws1) + lane;
    const float* __restrict__ A0 = sm.AT + rg * 512 + half * 256;
    float acc[3][2] = {{0.f, 0.f}, {0.f, 0.f}, {0.f, 0.f}};
#pragma unroll 4
    for (int d = 0; d < 256; d += 4) {
      float4 a[3];
#pragma unroll
      for (int r = 0; r < 3; ++r) a[r] = *(const float4*)&A0[r * 512 + d];
      float w0[4], w1[4];
#pragma unroll
      for (int i2 = 0; i2 < 4; ++i2) {
        w0[i2] = W[(d + i2) * 128];
        w1[i2] = W[(d + i2) * 128 + 64];
      }
#pragma unroll
      for (int i2 = 0; i2 < 4; ++i2)
#pragma unroll
        for (int r = 0; r < 3; ++r) {
          const float av = ((const float*)&a[r])[i2];
          acc[r][0] = fmaf(av, w0[i2], acc[r][0]);
          acc[r][1] = fmaf(av, w1[i2], acc[r][1]);
        }
    }
    float p[3];
#pragma unroll
    for (int r = 0; r < 3; ++r)
      p[r] = acc[r][0] * acc[r][0] + acc[r][1] * acc[r][1];
#pragma unroll
    for (int off = 32; off > 0; off >>= 1)
#pragma unroll
      for (int r = 0; r < 3; ++r) p[r] += __shfl_xor(p[r], off, 64);
    if (lane == 0) { rs2[wave][0] = p[0]; rs2[wave][1] = p[1]; rs2[wave][2] = p[2]; }
    __syncthreads();
#pragma unroll
    for (int r = 0; r < 3; ++r) {
      const float s = rs2[rowg][r] + rs2[rowg + 4][r];
      const float scale = rsqrtf(fmaxf(s, 1e-12f));
      R[(base + rg + r) * 256 + half * 128 + lane] = acc[r][0] * scale;
      R[(base + rg + r) * 256 + half * 128 + lane + 64] = acc[r][1] * scale;
    }
  }
  gbar(&bar[1]);                     // R complete device-wide

  // ================= Phase D1: NT[d][c] = R[neg_idx[c]][d] ================
  if (t < 128) {
    const int job = bid * 128 + t;   // 32768 f4 jobs total
    const int c = job & 511, d4 = job >> 9;
    const float4 v = *(const float4*)&R[neg_idx[c] * 256 + d4 * 4];
    NT[(d4 * 4 + 0) * 512 + c] = v.x;
    NT[(d4 * 4 + 1) * 512 + c] = v.y;
    NT[(d4 * 4 + 2) * 512 + c] = v.z;
    NT[(d4 * 4 + 3) * 512 + c] = v.w;
  }
  gbar(&bar[2]);                     // NT complete device-wide

  // ================= Phase D2: neg_aff + aff + rank + loss ================
  // Identical structure/numerics to the verified R2 k_neg (256 compute
  // threads; 512 help stage). Tie semantics: single ascending fmaf chain
  // d=0..255; aff computed by t<16 in the same loop order from staged P bits.
  {
    const int rowBase = (bid >> 2) * 16;
    const int colBase = (bid & 3) * 128;
    const bool first = (colBase == 0);
    if (t < 16) sm.d2.cntL[t] = 0;
    {
      const float4* __restrict__ s4 = (const float4*)R;
      for (int idx = t; idx < 32 * 64; idx += 512) {
        const int row = idx >> 6, c4 = idx & 63;
        const int rid = (row < 16) ? src_idx[rowBase + row]
                                   : pos_idx[rowBase + row - 16];
        *(float4*)&sm.d2.SP[row * 260 + c4 * 4] = s4[rid * 64 + c4];
      }
      if (first) {                   // src_emb copy to d_out
        float4* __restrict__ d4o = (float4*)out;
        for (int idx = t; idx < 16 * 64; idx += 512) {
          const int rr = idx >> 6, c4 = idx & 63;
          d4o[(rowBase + rr) * 64 + c4] = s4[src_idx[rowBase + rr] * 64 + c4];
        }
      }
    }
    __syncthreads();

    const int tc = t & 31;
    const int tr = (t >> 5) & 7;
    float acc[2][4];
#pragma unroll
    for (int r = 0; r < 2; ++r)
#pragma unroll
      for (int j = 0; j < 4; ++j) acc[r][j] = 0.f;
    float aff = 0.f;

    if (t < 256) {
      const float* __restrict__ B = NT + colBase + 4 * tc;
      const float* __restrict__ A0 = sm.d2.SP + tr * 260;
      const float* __restrict__ A1 = sm.d2.SP + (tr + 8) * 260;
      const float* __restrict__ SV = sm.d2.SP + t * 260;          // t<16 only
      const float* __restrict__ PV = sm.d2.SP + (16 + t) * 260;   // t<16 only
#pragma unroll 2
      for (int d4 = 0; d4 < 64; ++d4) {
        const int dd = d4 * 4;
        const float4 a0 = *(const float4*)&A0[dd];
        const float4 a1 = *(const float4*)&A1[dd];
        float4 b[4];
#pragma unroll
        for (int i2 = 0; i2 < 4; ++i2)
          b[i2] = *(const float4*)&B[(dd + i2) * 512];
        float4 sv, pv;
        if (t < 16) {
          sv = *(const float4*)&SV[dd];
          pv = *(const float4*)&PV[dd];
        }
#pragma unroll
        for (int i2 = 0; i2 < 4; ++i2) {
          const float va0 = ((const float*)&a0)[i2];
          const float va1 = ((const float*)&a1)[i2];
#pragma unroll
          for (int j = 0; j < 4; ++j) {
            const float vb = ((const float*)&b[i2])[j];
            acc[0][j] = fmaf(va0, vb, acc[0][j]);
            acc[1][j] = fmaf(va1, vb, acc[1][j]);
          }
          if (t < 16)
            aff = fmaf(((const float*)&sv)[i2], ((const float*)&pv)[i2], aff);
        }
      }
    }
    if (t < 16) sm.d2.affL[t] = aff;
    __syncthreads();

    float sp = 0.f;
    if (t < 256) {
      int cnt[2] = {0, 0};
#pragma unroll
      for (int r = 0; r < 2; ++r) {
        const float av = sm.d2.affL[tr + 8 * r];
#pragma unroll
        for (int j = 0; j < 4; ++j) {
          const float v = acc[r][j];
          sp += softplusf(v);
          cnt[r] += (v >= av) ? 1 : 0;
        }
      }
      if (cnt[0]) atomicAdd(&sm.d2.cntL[tr], cnt[0]);
      if (cnt[1]) atomicAdd(&sm.d2.cntL[tr + 8], cnt[1]);
    }
#pragma unroll
    for (int off = 32; off > 0; off >>= 1) sp += __shfl_down(sp, off, 64);
    if ((t & 63) == 0) sm.d2.wsum[t >> 6] = sp;
    if (first && t < 16) atomicAdd(spPos, softplusf(-aff));
    __syncthreads();
    if (t == 0)
      atomicAdd(spNeg, sm.d2.wsum[0] + sm.d2.wsum[1] + sm.d2.wsum[2] +
                           sm.d2.wsum[3] + sm.d2.wsum[4] + sm.d2.wsum[5] +
                           sm.d2.wsum[6] + sm.d2.wsum[7]);
    if (t < 16) atomicAdd(&rank[rowBase + t], sm.d2.cntL[t]);

    // ---- fused finalize: last block computes mrr + loss ----
    __threadfence();
    __syncthreads();
    if (t == 0) sm.d2.lastDone = (atomicAdd(done, 1) == NBLK - 1) ? 1 : 0;
    __syncthreads();
    if (sm.d2.lastDone) {
      float s = 0.f;
      for (int i = t; i < BATCH; i += 512) {
        const int rv = __hip_atomic_load(&rank[i], __ATOMIC_RELAXED,
                                         __HIP_MEMORY_SCOPE_AGENT);
        s += 1.f / (float)(rv + 1);
      }
#pragma unroll
      for (int off = 32; off > 0; off >>= 1) s += __shfl_down(s, off, 64);
      if ((t & 63) == 0) sm.d2.wsum[t >> 6] = s;
      __syncthreads();
      if (t == 0) {
        const float mrr = (sm.d2.wsum[0] + sm.d2.wsum[1] + sm.d2.wsum[2] +
                           sm.d2.wsum[3] + sm.d2.wsum[4] + sm.d2.wsum[5] +
                           sm.d2.wsum[6] + sm.d2.wsum[7]) * (1.f / 1024.f);
        const float p = __hip_atomic_load(spPos, __ATOMIC_RELAXED,
                                          __HIP_MEMORY_SCOPE_AGENT);
        const float n = __hip_atomic_load(spNeg, __ATOMIC_RELAXED,
                                          __HIP_MEMORY_SCOPE_AGENT);
        out[BATCH * 256]     = (p + n) * (1.f / 1024.f);
        out[BATCH * 256 + 1] = mrr;
      }
    }
  }
}

extern "C" void kernel_launch(void* const* d_in, const int* in_sizes, int n_in,
                              void* d_out, int out_size, void* d_ws, size_t ws_size,
                              hipStream_t stream) {
  const float* feat   = (const float*)d_in[1];
  const int* src_idx  = (const int*)d_in[2];
  const int* pos_idx  = (const int*)d_in[3];
  const int* neg_idx  = (const int*)d_in[4];
  const int* nb0      = (const int*)d_in[5];
  const int* nb1      = (const int*)d_in[6];
  const int* nb2      = (const int*)d_in[7];
  const float* ws0    = (const float*)d_in[8];
  const float* wn0    = (const float*)d_in[9];
  const float* ws1    = (const float*)d_in[10];
  const float* wn1    = (const float*)d_in[11];

  float* wsf = (float*)d_ws;
  unsigned short* X0 = (unsigned short*)d_ws;       // bf16[393216]
  unsigned short* Y0 = X0 + 393216;                 // bf16[393216]
  float* R     = wsf + 1966080;                     // 3072*256
  float* spPos = wsf + 2752512;
  float* spNeg = wsf + 2752513;
  int*   rank  = (int*)(wsf + 2752514);
  int*   done  = rank + 1024;
  int*   bar   = done + 1;                          // 3 counters
  float* NT    = wsf + 2753544;                     // float[256][512]
  float* out   = (float*)d_out;

  // zero spPos/spNeg/rank/done/bar (kernel boundary orders before k_fused)
  k_zero<<<1, 256, 0, stream>>>(spPos);
  // whole pipeline in ONE persistent kernel (256 blocks = 1/CU, co-resident)
  k_fused<<<NBLK, 512, 0, stream>>>(
      feat, src_idx, pos_idx, neg_idx, nb0, nb1, nb2,
      ws0, wn0, ws1, wn1, X0, Y0, R, NT, spPos, spNeg, rank, done, bar, out);
}

// Round 4
// 219.392 us; speedup vs baseline: 1.0895x; 1.0895x over previous
//
#include <hip/hip_runtime.h>
#include <math.h>

// Problem constants (from reference setup_inputs)
#define L0      3072
#define BATCH   1024
#define NNEG    512

// -------- workspace layout (float indices into d_ws) --------
// X0 : bf16[393216]            (feat @ w_self_0, bf16)
// Y0 : bf16[393216]            = X0 + 393216 elems
// H  : float @ 393216 (3072*512)   [A,B | C,D] layer-1 inputs
// R  : float @ 1966080 (3072*256)  layer-1 output, normalized
// spPos @ 2752512, spNeg @ 2752513, rank @ 2752514 (1024 ints), done @ rank+1024

__device__ __forceinline__ float bf2f(unsigned short u) {
  return __uint_as_float(((unsigned)u) << 16);
}
__device__ __forceinline__ void store_out(float v, float* p) { *p = v; }
__device__ __forceinline__ void store_out(float v, unsigned short* p) {
  unsigned x = __float_as_uint(v);                 // f32 -> bf16 RNE
  *p = (unsigned short)((x + 0x7fff + ((x >> 16) & 1)) >> 16);
}

// Half-split matmul, 6 rows x 256 cols per 512-thread block. (unchanged, R2)
template<int K, int AW, int HOFF, bool NORM, typename OutT>
__global__ __launch_bounds__(512) void k_mm(
    const float* __restrict__ Ain,
    const float* __restrict__ W0, const float* __restrict__ W1,
    OutT* __restrict__ Out, const int ldo, const int outHalfOff,
    float* __restrict__ zbuf, const int zcount) {
  __shared__ float AT[6 * AW];
  __shared__ float rs[8][3];
  const int t = threadIdx.x;
  if (zbuf != nullptr && blockIdx.x == 0)
    for (int z = t; z < zcount; z += 512) zbuf[z] = 0.f;
  const int base = blockIdx.x * 6;
  {
    const float4* __restrict__ src = (const float4*)(Ain + base * AW);
    float4* __restrict__ dst = (float4*)AT;
    for (int idx = t; idx < 6 * AW / 4; idx += 512) dst[idx] = src[idx];
  }
  __syncthreads();

  const int wave = t >> 6;
  const int half = wave >> 2;
  const int colg = (wave >> 1) & 1;
  const int rowg = wave & 1;
  const int rg = rowg * 3;
  const int col = colg * 64 + (t & 63);
  const float* __restrict__ W = (half ? W1 : W0) + col;
  const float* __restrict__ A0 = AT + rg * AW + half * HOFF;

  float acc[3] = {0.f, 0.f, 0.f};
#pragma unroll 4
  for (int d = 0; d < K; d += 4) {
    float4 a[3];
#pragma unroll
    for (int r = 0; r < 3; ++r) a[r] = *(const float4*)&A0[r * AW + d];
    float w[4];
#pragma unroll
    for (int i2 = 0; i2 < 4; ++i2) w[i2] = W[(d + i2) * 128];
#pragma unroll
    for (int i2 = 0; i2 < 4; ++i2)
#pragma unroll
      for (int r = 0; r < 3; ++r)
        acc[r] = fmaf(((const float*)&a[r])[i2], w[i2], acc[r]);
  }

  float scale[3] = {1.f, 1.f, 1.f};
  if (NORM) {
    float p[3];
#pragma unroll
    for (int r = 0; r < 3; ++r) p[r] = acc[r] * acc[r];
#pragma unroll
    for (int off = 32; off > 0; off >>= 1)
#pragma unroll
      for (int r = 0; r < 3; ++r) p[r] += __shfl_xor(p[r], off, 64);
    if ((t & 63) == 0) { rs[wave][0] = p[0]; rs[wave][1] = p[1]; rs[wave][2] = p[2]; }
    __syncthreads();
#pragma unroll
    for (int r = 0; r < 3; ++r) {
      const float s = rs[rowg][r] + rs[rowg + 2][r] + rs[rowg + 4][r] + rs[rowg + 6][r];
      scale[r] = rsqrtf(fmaxf(s, 1e-12f));
    }
  }
  OutT* __restrict__ O = Out + half * outHalfOff;
#pragma unroll
  for (int r = 0; r < 3; ++r)
    store_out(acc[r] * scale[r], &O[(base + rg + r) * ldo + col]);
}

// Fused layer-0 + layer-1 aggregation, bf16 gathers, ONE barrier. (unchanged, R2)
__global__ __launch_bounds__(640) void k_aggregate(
    const unsigned short* __restrict__ X0, const unsigned short* __restrict__ Y0,
    const int* __restrict__ nb0, const int* __restrict__ nb1,
    const int* __restrict__ nb2, float* __restrict__ H) {
  __shared__ float gB[10][128], gC[10][128], gD[10][128];
  const int i = blockIdx.x;
  const int t = threadIdx.x;
  const int n0 = nb0[i];
  const int j = t >> 6;
  const int lam = t & 63;
  const int r = i * 10 + j;
  int myidx = 0;
  if (lam < 25) myidx = nb2[r * 25 + lam];
  else if (lam == 25) myidx = nb1[r];
  const int c8 = lam & 15;
  const int sub = lam >> 4;

  float d8[8];
#pragma unroll
  for (int e = 0; e < 8; ++e) d8[e] = 0.f;
#pragma unroll
  for (int m = 0; m < 7; ++m) {
    const int k = sub + 4 * m;
    const int ridx = __shfl(myidx, k, 64);
    if (k < 25) {
      const float4 raw = *(const float4*)(Y0 + ridx * 128 + c8 * 8);
      const unsigned short* u = (const unsigned short*)&raw;
#pragma unroll
      for (int e = 0; e < 8; ++e) d8[e] += bf2f(u[e]);
    }
  }
#pragma unroll
  for (int e = 0; e < 8; ++e) d8[e] += __shfl_xor(d8[e], 16, 64);
#pragma unroll
  for (int e = 0; e < 8; ++e) d8[e] += __shfl_xor(d8[e], 32, 64);

  const int r1 = __shfl(myidx, 25, 64);
  if (sub == 0) {
#pragma unroll
    for (int e = 0; e < 8; ++e) gD[j][c8 * 8 + e] = fmaxf(d8[e] * 0.04f, 0.f);
    const float4 raw = *(const float4*)(Y0 + r1 * 128 + c8 * 8);
    const unsigned short* u = (const unsigned short*)&raw;
#pragma unroll
    for (int e = 0; e < 8; ++e) gB[j][c8 * 8 + e] = bf2f(u[e]);
  } else if (sub == 1) {
    const float4 raw = *(const float4*)(X0 + r1 * 128 + c8 * 8);
    const unsigned short* u = (const unsigned short*)&raw;
#pragma unroll
    for (int e = 0; e < 8; ++e) gC[j][c8 * 8 + e] = fmaxf(bf2f(u[e]), 0.f);
  }
  __syncthreads();

  if (t < 512) {
    const int q = t >> 7, c = t & 127;
    float v;
    if (q == 0) {
      v = fmaxf(bf2f(X0[n0 * 128 + c]), 0.f);
    } else {
      const float* g = (q == 1) ? &gB[0][0] : (q == 2) ? &gC[0][0] : &gD[0][0];
      float s = 0.f;
#pragma unroll
      for (int jj = 0; jj < 10; ++jj) s += g[jj * 128 + c];
      v = s * 0.1f;
      if (q == 1) v = fmaxf(v, 0.f);
    }
    H[i * 512 + t] = v;
  }
}

__device__ __forceinline__ float softplusf(float x) {
  return fmaxf(x, 0.f) + log1pf(expf(-fabsf(x)));
}

// neg_aff v4: 1024 blocks (8 src x 64 neg) x 256 threads, 16.6 KB LDS ->
// 4 blocks/CU = 16 waves/CU (5x the wave count of v3's 1 block/CU).
// No NT / no k_prep: each lane owns ONE neg row of R and streams it
// sequentially (f4, unroll-4 -> 4 loads in flight, L2-hot everywhere; no
// producer-XCD dirty-line asymmetry). S+P staged in LDS; A-reads are
// wave-broadcast ds_read_b128 (wave index == row group -> uniform addr).
// Per thread: rows {rowg, rowg+4} x 1 col = 2 accs.
// Tie semantics: single ascending fmaf chain (d4 -> i2); aff computed by
// lanes t<8 in the SAME loop order from staged P bits -> dot(S,P) bitwise
// == dot(S,N) whenever pos_idx==neg_idx (stable positive-last rank:
// rank = #(neg >= aff)). Finalize fused via done-counter (target 1023).
__global__ __launch_bounds__(256) void k_neg(
    const float* __restrict__ O, const int* __restrict__ src_idx,
    const int* __restrict__ pos_idx, const int* __restrict__ neg_idx,
    float* __restrict__ out_src, int* __restrict__ rank,
    float* __restrict__ spPos, float* __restrict__ spNeg,
    int* __restrict__ done) {
  __shared__ float SP[16 * 260];     // rows [0,8) src, [8,16) pos
  __shared__ float affL[8];
  __shared__ int cntL[8];
  __shared__ float wsum[4];
  __shared__ int lastDone;
  const int t = threadIdx.x;
  const int rowBase = (blockIdx.x >> 3) * 8;   // 128 row-tiles
  const int colBase = (blockIdx.x & 7) * 64;   // 8 col-tiles
  const bool first = (colBase == 0);

  // stage S (8 rows) + P (8 rows), full K=256, coalesced f4 gathers
  {
    const float4* __restrict__ s4 = (const float4*)O;
#pragma unroll
    for (int idx = t; idx < 16 * 64; idx += 256) {
      const int row = idx >> 6, c4 = idx & 63;
      const int rid = (row < 8) ? src_idx[rowBase + row]
                                : pos_idx[rowBase + row - 8];
      *(float4*)&SP[row * 260 + c4 * 4] = s4[rid * 64 + c4];
    }
  }
  if (first) {  // src_emb copy to d_out (8 rows x 64 float4)
    const float4* __restrict__ s4 = (const float4*)O;
    float4* __restrict__ d4o = (float4*)out_src;
#pragma unroll
    for (int idx = t; idx < 8 * 64; idx += 256) {
      const int rr = idx >> 6, c4 = idx & 63;
      d4o[(rowBase + rr) * 64 + c4] = s4[src_idx[rowBase + rr] * 64 + c4];
    }
  }
  __syncthreads();

  const int cl = t & 63;            // col within tile (also lane)
  const int rowg = t >> 6;          // wave index = row group: rows {rowg, rowg+4}
  const float* __restrict__ Bp = O + neg_idx[colBase + cl] * 256;
  const float* __restrict__ A0 = SP + rowg * 260;
  const float* __restrict__ A1 = SP + (rowg + 4) * 260;
  const float* __restrict__ SV = SP + t * 260;          // t<8 only
  const float* __restrict__ PV = SP + (8 + t) * 260;    // t<8 only

  float acc0 = 0.f, acc1 = 0.f, aff = 0.f;
#pragma unroll 4
  for (int d4 = 0; d4 < 64; ++d4) {
    const int dd = d4 * 4;
    const float4 b  = *(const float4*)&Bp[dd];    // own neg row, sequential
    const float4 a0 = *(const float4*)&A0[dd];    // wave-broadcast LDS
    const float4 a1 = *(const float4*)&A1[dd];
    float4 sv, pv;
    if (t < 8) {
      sv = *(const float4*)&SV[dd];
      pv = *(const float4*)&PV[dd];
    }
#pragma unroll
    for (int i2 = 0; i2 < 4; ++i2) {
      const float vb = ((const float*)&b)[i2];
      acc0 = fmaf(((const float*)&a0)[i2], vb, acc0);
      acc1 = fmaf(((const float*)&a1)[i2], vb, acc1);
      if (t < 8)
        aff = fmaf(((const float*)&sv)[i2], ((const float*)&pv)[i2], aff);
    }
  }
  if (t < 8) affL[t] = aff;
  __syncthreads();

  // per-wave reduce: all 64 lanes of wave w share rows {w, w+4}
  float sp = softplusf(acc0) + softplusf(acc1);
  int c0 = (acc0 >= affL[rowg]) ? 1 : 0;
  int c1 = (acc1 >= affL[rowg + 4]) ? 1 : 0;
#pragma unroll
  for (int off = 32; off > 0; off >>= 1) {
    sp += __shfl_down(sp, off, 64);
    c0 += __shfl_down(c0, off, 64);
    c1 += __shfl_down(c1, off, 64);
  }
  if ((t & 63) == 0) {
    cntL[rowg] = c0;
    cntL[rowg + 4] = c1;
    wsum[rowg] = sp;
  }
  __syncthreads();
  if (t < 8) atomicAdd(&rank[rowBase + t], cntL[t]);
  if (t == 0) atomicAdd(spNeg, wsum[0] + wsum[1] + wsum[2] + wsum[3]);
  if (first && t < 8) atomicAdd(spPos, softplusf(-affL[t]));

  // ---- fused finalize: last block computes mrr + loss ----
  __threadfence();
  __syncthreads();
  if (t == 0) lastDone = (atomicAdd(done, 1) == 1023) ? 1 : 0;
  __syncthreads();
  if (lastDone) {
    float s = 0.f;
    for (int i = t; i < BATCH; i += 256) {
      const int rv = __hip_atomic_load(&rank[i], __ATOMIC_RELAXED,
                                       __HIP_MEMORY_SCOPE_AGENT);
      s += 1.f / (float)(rv + 1);
    }
#pragma unroll
    for (int off = 32; off > 0; off >>= 1) s += __shfl_down(s, off, 64);
    if ((t & 63) == 0) wsum[t >> 6] = s;
    __syncthreads();
    if (t == 0) {
      const float mrr = (wsum[0] + wsum[1] + wsum[2] + wsum[3]) * (1.f / 1024.f);
      const float p = __hip_atomic_load(spPos, __ATOMIC_RELAXED,
                                        __HIP_MEMORY_SCOPE_AGENT);
      const float n = __hip_atomic_load(spNeg, __ATOMIC_RELAXED,
                                        __HIP_MEMORY_SCOPE_AGENT);
      out_src[BATCH * 256]     = (p + n) * (1.f / 1024.f);
      out_src[BATCH * 256 + 1] = mrr;
    }
  }
}

extern "C" void kernel_launch(void* const* d_in, const int* in_sizes, int n_in,
                              void* d_out, int out_size, void* d_ws, size_t ws_size,
                              hipStream_t stream) {
  const float* feat   = (const float*)d_in[1];
  const int* src_idx  = (const int*)d_in[2];
  const int* pos_idx  = (const int*)d_in[3];
  const int* neg_idx  = (const int*)d_in[4];
  const int* nb0      = (const int*)d_in[5];
  const int* nb1      = (const int*)d_in[6];
  const int* nb2      = (const int*)d_in[7];
  const float* ws0    = (const float*)d_in[8];
  const float* wn0    = (const float*)d_in[9];
  const float* ws1    = (const float*)d_in[10];
  const float* wn1    = (const float*)d_in[11];

  float* wsf = (float*)d_ws;
  unsigned short* X0 = (unsigned short*)d_ws;       // bf16[393216]
  unsigned short* Y0 = X0 + 393216;                 // bf16[393216]
  float* H     = wsf + 393216;                      // 3072*512
  float* R     = wsf + 1966080;                     // 3072*256
  float* spPos = wsf + 2752512;
  float* spNeg = wsf + 2752513;
  int*   rank  = (int*)(wsf + 2752514);
  int*   done  = rank + 1024;
  float* out   = (float*)d_out;

  // X0 = bf16(feat@ws0), Y0 = bf16(feat@wn0); block 0 zeroes spPos/spNeg/rank/done
  k_mm<128, 128, 0, false, unsigned short><<<L0 / 6, 512, 0, stream>>>(
      feat, ws0, wn0, X0, 128, 393216, spPos, 1027);
  k_aggregate<<<L0, 640, 0, stream>>>(X0, Y0, nb0, nb1, nb2, H);
  // R[:, :128] = H[:, :256]@ws1 ; R[:, 128:] = H[:, 256:]@wn1 ; + L2-norm
  k_mm<256, 512, 256, true, float><<<L0 / 6, 512, 0, stream>>>(
      H, ws1, wn1, R, 256, 128, nullptr, 0);
  // 1024 blocks = 128 row-tiles x 8 col-tiles; finalize fused (done-counter)
  k_neg<<<1024, 256, 0, stream>>>(
      R, src_idx, pos_idx, neg_idx, out, rank, spPos, spNeg, done);
}

// Round 5
// 182.314 us; speedup vs baseline: 1.3111x; 1.2034x over previous
//
#include <hip/hip_runtime.h>
#include <math.h>

// Problem constants (from reference setup_inputs)
#define L0      3072
#define BATCH   1024
#define NNEG    512

// -------- workspace layout (float indices into d_ws) --------
// X0 : bf16[393216]            (feat @ w_self_0, bf16)
// Y0 : bf16[393216]            = X0 + 393216 elems
// H  : float @ 393216 (3072*512)   [A,B | C,D] layer-1 inputs
// R  : float @ 1966080 (3072*256)  layer-1 output, normalized
// spPos @ 2752512, spNeg @ 2752513, rank @ 2752514 (1024 ints),
// done @ rank+1024, NT @ 2753540 (float[256][512], neg_emb^T dense)

__device__ __forceinline__ float bf2f(unsigned short u) {
  return __uint_as_float(((unsigned)u) << 16);
}
__device__ __forceinline__ void store_out(float v, float* p) { *p = v; }
__device__ __forceinline__ void store_out(float v, unsigned short* p) {
  unsigned x = __float_as_uint(v);                 // f32 -> bf16 RNE
  *p = (unsigned short)((x + 0x7fff + ((x >> 16) & 1)) >> 16);
}

// Half-split matmul, 6 rows x 256 cols per 512-thread block. (unchanged, R2)
template<int K, int AW, int HOFF, bool NORM, typename OutT>
__global__ __launch_bounds__(512) void k_mm(
    const float* __restrict__ Ain,
    const float* __restrict__ W0, const float* __restrict__ W1,
    OutT* __restrict__ Out, const int ldo, const int outHalfOff,
    float* __restrict__ zbuf, const int zcount) {
  __shared__ float AT[6 * AW];
  __shared__ float rs[8][3];
  const int t = threadIdx.x;
  if (zbuf != nullptr && blockIdx.x == 0)
    for (int z = t; z < zcount; z += 512) zbuf[z] = 0.f;
  const int base = blockIdx.x * 6;
  {
    const float4* __restrict__ src = (const float4*)(Ain + base * AW);
    float4* __restrict__ dst = (float4*)AT;
    for (int idx = t; idx < 6 * AW / 4; idx += 512) dst[idx] = src[idx];
  }
  __syncthreads();

  const int wave = t >> 6;
  const int half = wave >> 2;
  const int colg = (wave >> 1) & 1;
  const int rowg = wave & 1;
  const int rg = rowg * 3;
  const int col = colg * 64 + (t & 63);
  const float* __restrict__ W = (half ? W1 : W0) + col;
  const float* __restrict__ A0 = AT + rg * AW + half * HOFF;

  float acc[3] = {0.f, 0.f, 0.f};
#pragma unroll 4
  for (int d = 0; d < K; d += 4) {
    float4 a[3];
#pragma unroll
    for (int r = 0; r < 3; ++r) a[r] = *(const float4*)&A0[r * AW + d];
    float w[4];
#pragma unroll
    for (int i2 = 0; i2 < 4; ++i2) w[i2] = W[(d + i2) * 128];
#pragma unroll
    for (int i2 = 0; i2 < 4; ++i2)
#pragma unroll
      for (int r = 0; r < 3; ++r)
        acc[r] = fmaf(((const float*)&a[r])[i2], w[i2], acc[r]);
  }

  float scale[3] = {1.f, 1.f, 1.f};
  if (NORM) {
    float p[3];
#pragma unroll
    for (int r = 0; r < 3; ++r) p[r] = acc[r] * acc[r];
#pragma unroll
    for (int off = 32; off > 0; off >>= 1)
#pragma unroll
      for (int r = 0; r < 3; ++r) p[r] += __shfl_xor(p[r], off, 64);
    if ((t & 63) == 0) { rs[wave][0] = p[0]; rs[wave][1] = p[1]; rs[wave][2] = p[2]; }
    __syncthreads();
#pragma unroll
    for (int r = 0; r < 3; ++r) {
      const float s = rs[rowg][r] + rs[rowg + 2][r] + rs[rowg + 4][r] + rs[rowg + 6][r];
      scale[r] = rsqrtf(fmaxf(s, 1e-12f));
    }
  }
  OutT* __restrict__ O = Out + half * outHalfOff;
#pragma unroll
  for (int r = 0; r < 3; ++r)
    store_out(acc[r] * scale[r], &O[(base + rg + r) * ldo + col]);
}

// Fused layer-0 + layer-1 aggregation, bf16 gathers, ONE barrier. (unchanged, R2)
__global__ __launch_bounds__(640) void k_aggregate(
    const unsigned short* __restrict__ X0, const unsigned short* __restrict__ Y0,
    const int* __restrict__ nb0, const int* __restrict__ nb1,
    const int* __restrict__ nb2, float* __restrict__ H) {
  __shared__ float gB[10][128], gC[10][128], gD[10][128];
  const int i = blockIdx.x;
  const int t = threadIdx.x;
  const int n0 = nb0[i];
  const int j = t >> 6;
  const int lam = t & 63;
  const int r = i * 10 + j;
  int myidx = 0;
  if (lam < 25) myidx = nb2[r * 25 + lam];
  else if (lam == 25) myidx = nb1[r];
  const int c8 = lam & 15;
  const int sub = lam >> 4;

  float d8[8];
#pragma unroll
  for (int e = 0; e < 8; ++e) d8[e] = 0.f;
#pragma unroll
  for (int m = 0; m < 7; ++m) {
    const int k = sub + 4 * m;
    const int ridx = __shfl(myidx, k, 64);
    if (k < 25) {
      const float4 raw = *(const float4*)(Y0 + ridx * 128 + c8 * 8);
      const unsigned short* u = (const unsigned short*)&raw;
#pragma unroll
      for (int e = 0; e < 8; ++e) d8[e] += bf2f(u[e]);
    }
  }
#pragma unroll
  for (int e = 0; e < 8; ++e) d8[e] += __shfl_xor(d8[e], 16, 64);
#pragma unroll
  for (int e = 0; e < 8; ++e) d8[e] += __shfl_xor(d8[e], 32, 64);

  const int r1 = __shfl(myidx, 25, 64);
  if (sub == 0) {
#pragma unroll
    for (int e = 0; e < 8; ++e) gD[j][c8 * 8 + e] = fmaxf(d8[e] * 0.04f, 0.f);
    const float4 raw = *(const float4*)(Y0 + r1 * 128 + c8 * 8);
    const unsigned short* u = (const unsigned short*)&raw;
#pragma unroll
    for (int e = 0; e < 8; ++e) gB[j][c8 * 8 + e] = bf2f(u[e]);
  } else if (sub == 1) {
    const float4 raw = *(const float4*)(X0 + r1 * 128 + c8 * 8);
    const unsigned short* u = (const unsigned short*)&raw;
#pragma unroll
    for (int e = 0; e < 8; ++e) gC[j][c8 * 8 + e] = fmaxf(bf2f(u[e]), 0.f);
  }
  __syncthreads();

  if (t < 512) {
    const int q = t >> 7, c = t & 127;
    float v;
    if (q == 0) {
      v = fmaxf(bf2f(X0[n0 * 128 + c]), 0.f);
    } else {
      const float* g = (q == 1) ? &gB[0][0] : (q == 2) ? &gC[0][0] : &gD[0][0];
      float s = 0.f;
#pragma unroll
      for (int jj = 0; jj < 10; ++jj) s += g[jj * 128 + c];
      v = s * 0.1f;
      if (q == 1) v = fmaxf(v, 0.f);
    }
    H[i * 512 + t] = v;
  }
}

__device__ __forceinline__ float softplusf(float x) {
  return fmaxf(x, 0.f) + log1pf(expf(-fabsf(x)));
}

// NT[d][c] = R[neg_idx[c]][d] — dense transposed neg embeddings (0.5 MB).
// Reads: f4 gathers (L2-hot). Writes: coalesced 256B per wave per d-row.
__global__ __launch_bounds__(256) void k_prep(
    const float* __restrict__ R, const int* __restrict__ neg_idx,
    float* __restrict__ NT) {
  const int idx = blockIdx.x * 256 + threadIdx.x;   // 128 blocks: 32768 f4 jobs
  const int c = idx & 511;
  const int d4 = idx >> 9;                          // 0..63
  const float4 v = *(const float4*)&R[neg_idx[c] * 256 + d4 * 4];
#pragma unroll
  for (int i2 = 0; i2 < 4; ++i2)
    NT[(d4 * 4 + i2) * 512 + c] = ((const float*)&v)[i2];
}

// neg_aff v5 = v3's coalesced NT-streaming B + v4's high-occupancy grid.
// 512 blocks (8 src x 128 neg) x 256 threads, 16.6 KB LDS -> 2 blocks/CU,
// 8 waves/CU, all 256 CUs. Thread = 2 rows x 2 cols (4 acc).
// B: global_load_dwordx2 from NT — wave reads 512B CONTIGUOUS per instr
// (v4's fatal flaw was 64-way address divergence; NT fixes it). A/S/P from
// LDS, wave-uniform broadcast ds_read_b128 (tr = t>>6 is wave index).
// Tie semantics (verified pattern): single ascending fmaf chain (d4 -> i2)
// per output; aff computed by lanes t<8 in the SAME loop order from staged
// P bits; NT holds exact R bits -> dot(S,P) bitwise == dot(S,N) whenever
// pos_idx==neg_idx (stable positive-last rank: rank = #(neg >= aff)).
// Finalize fused via done-counter (target 511).
__global__ __launch_bounds__(256) void k_neg(
    const float* __restrict__ O, const float* __restrict__ NT,
    const int* __restrict__ src_idx, const int* __restrict__ pos_idx,
    float* __restrict__ out_src, int* __restrict__ rank,
    float* __restrict__ spPos, float* __restrict__ spNeg,
    int* __restrict__ done) {
  __shared__ float SP[16 * 260];     // rows [0,8) src, [8,16) pos
  __shared__ float affL[8];
  __shared__ int cntL[8];
  __shared__ float wsum[4];
  __shared__ int lastDone;
  const int t = threadIdx.x;
  const int rowBase = (blockIdx.x >> 2) * 8;   // 128 row-tiles
  const int colBase = (blockIdx.x & 3) * 128;  // 4 col-tiles
  const bool first = (colBase == 0);

  // stage S (8 rows) + P (8 rows), full K=256, coalesced f4 gathers
  {
    const float4* __restrict__ s4 = (const float4*)O;
#pragma unroll
    for (int idx = t; idx < 16 * 64; idx += 256) {
      const int row = idx >> 6, c4 = idx & 63;
      const int rid = (row < 8) ? src_idx[rowBase + row]
                                : pos_idx[rowBase + row - 8];
      *(float4*)&SP[row * 260 + c4 * 4] = s4[rid * 64 + c4];
    }
  }
  if (first) {  // src_emb copy to d_out (8 rows x 64 float4)
    const float4* __restrict__ s4 = (const float4*)O;
    float4* __restrict__ d4o = (float4*)out_src;
#pragma unroll
    for (int idx = t; idx < 8 * 64; idx += 256) {
      const int rr = idx >> 6, c4 = idx & 63;
      d4o[(rowBase + rr) * 64 + c4] = s4[src_idx[rowBase + rr] * 64 + c4];
    }
  }
  __syncthreads();

  const int tc = t & 63;            // cols {2tc, 2tc+1} within the 128
  const int tr = t >> 6;            // wave index = row group: rows {tr, tr+4}
  const float* __restrict__ B = NT + colBase + 2 * tc;
  const float* __restrict__ A0 = SP + tr * 260;
  const float* __restrict__ A1 = SP + (tr + 4) * 260;
  const float* __restrict__ SV = SP + t * 260;          // t<8 only
  const float* __restrict__ PV = SP + (8 + t) * 260;    // t<8 only

  float acc00 = 0.f, acc01 = 0.f, acc10 = 0.f, acc11 = 0.f, aff = 0.f;
#pragma unroll 4
  for (int d4 = 0; d4 < 64; ++d4) {
    const int dd = d4 * 4;
    const float4 a0 = *(const float4*)&A0[dd];    // wave-broadcast LDS
    const float4 a1 = *(const float4*)&A1[dd];
    float2 b[4];
#pragma unroll
    for (int i2 = 0; i2 < 4; ++i2)
      b[i2] = *(const float2*)&B[(dd + i2) * 512]; // 512B contiguous per wave
    float4 sv, pv;
    if (t < 8) {
      sv = *(const float4*)&SV[dd];
      pv = *(const float4*)&PV[dd];
    }
#pragma unroll
    for (int i2 = 0; i2 < 4; ++i2) {
      const float va0 = ((const float*)&a0)[i2];
      const float va1 = ((const float*)&a1)[i2];
      acc00 = fmaf(va0, b[i2].x, acc00);
      acc01 = fmaf(va0, b[i2].y, acc01);
      acc10 = fmaf(va1, b[i2].x, acc10);
      acc11 = fmaf(va1, b[i2].y, acc11);
      if (t < 8)
        aff = fmaf(((const float*)&sv)[i2], ((const float*)&pv)[i2], aff);
    }
  }
  if (t < 8) affL[t] = aff;
  __syncthreads();

  // per-wave reduce: all 64 lanes of wave w share rows {w, w+4}
  float sp = softplusf(acc00) + softplusf(acc01) +
             softplusf(acc10) + softplusf(acc11);
  const float av0 = affL[tr], av1 = affL[tr + 4];
  int c0 = ((acc00 >= av0) ? 1 : 0) + ((acc01 >= av0) ? 1 : 0);
  int c1 = ((acc10 >= av1) ? 1 : 0) + ((acc11 >= av1) ? 1 : 0);
#pragma unroll
  for (int off = 32; off > 0; off >>= 1) {
    sp += __shfl_down(sp, off, 64);
    c0 += __shfl_down(c0, off, 64);
    c1 += __shfl_down(c1, off, 64);
  }
  if ((t & 63) == 0) {
    cntL[tr] = c0;
    cntL[tr + 4] = c1;
    wsum[tr] = sp;
  }
  __syncthreads();
  if (t < 8) atomicAdd(&rank[rowBase + t], cntL[t]);
  if (t == 0) atomicAdd(spNeg, wsum[0] + wsum[1] + wsum[2] + wsum[3]);
  if (first && t < 8) atomicAdd(spPos, softplusf(-affL[t]));

  // ---- fused finalize: last block computes mrr + loss ----
  __threadfence();
  __syncthreads();
  if (t == 0) lastDone = (atomicAdd(done, 1) == 511) ? 1 : 0;
  __syncthreads();
  if (lastDone) {
    float s = 0.f;
    for (int i = t; i < BATCH; i += 256) {
      const int rv = __hip_atomic_load(&rank[i], __ATOMIC_RELAXED,
                                       __HIP_MEMORY_SCOPE_AGENT);
      s += 1.f / (float)(rv + 1);
    }
#pragma unroll
    for (int off = 32; off > 0; off >>= 1) s += __shfl_down(s, off, 64);
    if ((t & 63) == 0) wsum[t >> 6] = s;
    __syncthreads();
    if (t == 0) {
      const float mrr = (wsum[0] + wsum[1] + wsum[2] + wsum[3]) * (1.f / 1024.f);
      const float p = __hip_atomic_load(spPos, __ATOMIC_RELAXED,
                                        __HIP_MEMORY_SCOPE_AGENT);
      const float n = __hip_atomic_load(spNeg, __ATOMIC_RELAXED,
                                        __HIP_MEMORY_SCOPE_AGENT);
      out_src[BATCH * 256]     = (p + n) * (1.f / 1024.f);
      out_src[BATCH * 256 + 1] = mrr;
    }
  }
}

extern "C" void kernel_launch(void* const* d_in, const int* in_sizes, int n_in,
                              void* d_out, int out_size, void* d_ws, size_t ws_size,
                              hipStream_t stream) {
  const float* feat   = (const float*)d_in[1];
  const int* src_idx  = (const int*)d_in[2];
  const int* pos_idx  = (const int*)d_in[3];
  const int* neg_idx  = (const int*)d_in[4];
  const int* nb0      = (const int*)d_in[5];
  const int* nb1      = (const int*)d_in[6];
  const int* nb2      = (const int*)d_in[7];
  const float* ws0    = (const float*)d_in[8];
  const float* wn0    = (const float*)d_in[9];
  const float* ws1    = (const float*)d_in[10];
  const float* wn1    = (const float*)d_in[11];

  float* wsf = (float*)d_ws;
  unsigned short* X0 = (unsigned short*)d_ws;       // bf16[393216]
  unsigned short* Y0 = X0 + 393216;                 // bf16[393216]
  float* H     = wsf + 393216;                      // 3072*512
  float* R     = wsf + 1966080;                     // 3072*256
  float* spPos = wsf + 2752512;
  float* spNeg = wsf + 2752513;
  int*   rank  = (int*)(wsf + 2752514);
  int*   done  = rank + 1024;
  float* NT    = wsf + 2753540;                     // float[256][512]
  float* out   = (float*)d_out;

  // X0 = bf16(feat@ws0), Y0 = bf16(feat@wn0); block 0 zeroes spPos/spNeg/rank/done
  k_mm<128, 128, 0, false, unsigned short><<<L0 / 6, 512, 0, stream>>>(
      feat, ws0, wn0, X0, 128, 393216, spPos, 1027);
  k_aggregate<<<L0, 640, 0, stream>>>(X0, Y0, nb0, nb1, nb2, H);
  // R[:, :128] = H[:, :256]@ws1 ; R[:, 128:] = H[:, 256:]@wn1 ; + L2-norm
  k_mm<256, 512, 256, true, float><<<L0 / 6, 512, 0, stream>>>(
      H, ws1, wn1, R, 256, 128, nullptr, 0);
  // NT = neg_emb^T dense (0.5 MB)
  k_prep<<<128, 256, 0, stream>>>(R, neg_idx, NT);
  // 512 blocks = 128 row-tiles x 4 col-tiles; finalize fused (done-counter)
  k_neg<<<512, 256, 0, stream>>>(
      R, NT, src_idx, pos_idx, out, rank, spPos, spNeg, done);
}

// Round 6
// 178.425 us; speedup vs baseline: 1.3397x; 1.0218x over previous
//
#include <hip/hip_runtime.h>
#include <math.h>

// Problem constants (from reference setup_inputs)
#define L0      3072
#define BATCH   1024
#define NNEG    512

// -------- workspace layout (float indices into d_ws) --------
// X0 : bf16[393216]            (feat @ w_self_0, bf16)
// Y0 : bf16[393216]            = X0 + 393216 elems
// H  : float @ 393216 (3072*512)   [A,B | C,D] layer-1 inputs
// R  : float @ 1966080 (3072*256)  layer-1 output, normalized
// spPos @ 2752512, spNeg @ 2752513, rank @ 2752514 (1024 ints),
// done @ rank+1024, NT @ 2753540 (float[256][512], neg_emb^T dense)

__device__ __forceinline__ float bf2f(unsigned short u) {
  return __uint_as_float(((unsigned)u) << 16);
}
__device__ __forceinline__ void store_out(float v, float* p) { *p = v; }
__device__ __forceinline__ void store_out(float v, unsigned short* p) {
  unsigned x = __float_as_uint(v);                 // f32 -> bf16 RNE
  *p = (unsigned short)((x + 0x7fff + ((x >> 16) & 1)) >> 16);
}

// Half-split matmul, 6 rows x 256 cols per 512-thread block. (unchanged, R2)
template<int K, int AW, int HOFF, bool NORM, typename OutT>
__global__ __launch_bounds__(512) void k_mm(
    const float* __restrict__ Ain,
    const float* __restrict__ W0, const float* __restrict__ W1,
    OutT* __restrict__ Out, const int ldo, const int outHalfOff,
    float* __restrict__ zbuf, const int zcount) {
  __shared__ float AT[6 * AW];
  __shared__ float rs[8][3];
  const int t = threadIdx.x;
  if (zbuf != nullptr && blockIdx.x == 0)
    for (int z = t; z < zcount; z += 512) zbuf[z] = 0.f;
  const int base = blockIdx.x * 6;
  {
    const float4* __restrict__ src = (const float4*)(Ain + base * AW);
    float4* __restrict__ dst = (float4*)AT;
    for (int idx = t; idx < 6 * AW / 4; idx += 512) dst[idx] = src[idx];
  }
  __syncthreads();

  const int wave = t >> 6;
  const int half = wave >> 2;
  const int colg = (wave >> 1) & 1;
  const int rowg = wave & 1;
  const int rg = rowg * 3;
  const int col = colg * 64 + (t & 63);
  const float* __restrict__ W = (half ? W1 : W0) + col;
  const float* __restrict__ A0 = AT + rg * AW + half * HOFF;

  float acc[3] = {0.f, 0.f, 0.f};
#pragma unroll 4
  for (int d = 0; d < K; d += 4) {
    float4 a[3];
#pragma unroll
    for (int r = 0; r < 3; ++r) a[r] = *(const float4*)&A0[r * AW + d];
    float w[4];
#pragma unroll
    for (int i2 = 0; i2 < 4; ++i2) w[i2] = W[(d + i2) * 128];
#pragma unroll
    for (int i2 = 0; i2 < 4; ++i2)
#pragma unroll
      for (int r = 0; r < 3; ++r)
        acc[r] = fmaf(((const float*)&a[r])[i2], w[i2], acc[r]);
  }

  float scale[3] = {1.f, 1.f, 1.f};
  if (NORM) {
    float p[3];
#pragma unroll
    for (int r = 0; r < 3; ++r) p[r] = acc[r] * acc[r];
#pragma unroll
    for (int off = 32; off > 0; off >>= 1)
#pragma unroll
      for (int r = 0; r < 3; ++r) p[r] += __shfl_xor(p[r], off, 64);
    if ((t & 63) == 0) { rs[wave][0] = p[0]; rs[wave][1] = p[1]; rs[wave][2] = p[2]; }
    __syncthreads();
#pragma unroll
    for (int r = 0; r < 3; ++r) {
      const float s = rs[rowg][r] + rs[rowg + 2][r] + rs[rowg + 4][r] + rs[rowg + 6][r];
      scale[r] = rsqrtf(fmaxf(s, 1e-12f));
    }
  }
  OutT* __restrict__ O = Out + half * outHalfOff;
#pragma unroll
  for (int r = 0; r < 3; ++r)
    store_out(acc[r] * scale[r], &O[(base + rg + r) * ldo + col]);
}

// Fused layer-0 + layer-1 aggregation, bf16 gathers, ONE barrier. (unchanged, R2)
__global__ __launch_bounds__(640) void k_aggregate(
    const unsigned short* __restrict__ X0, const unsigned short* __restrict__ Y0,
    const int* __restrict__ nb0, const int* __restrict__ nb1,
    const int* __restrict__ nb2, float* __restrict__ H) {
  __shared__ float gB[10][128], gC[10][128], gD[10][128];
  const int i = blockIdx.x;
  const int t = threadIdx.x;
  const int n0 = nb0[i];
  const int j = t >> 6;
  const int lam = t & 63;
  const int r = i * 10 + j;
  int myidx = 0;
  if (lam < 25) myidx = nb2[r * 25 + lam];
  else if (lam == 25) myidx = nb1[r];
  const int c8 = lam & 15;
  const int sub = lam >> 4;

  float d8[8];
#pragma unroll
  for (int e = 0; e < 8; ++e) d8[e] = 0.f;
#pragma unroll
  for (int m = 0; m < 7; ++m) {
    const int k = sub + 4 * m;
    const int ridx = __shfl(myidx, k, 64);
    if (k < 25) {
      const float4 raw = *(const float4*)(Y0 + ridx * 128 + c8 * 8);
      const unsigned short* u = (const unsigned short*)&raw;
#pragma unroll
      for (int e = 0; e < 8; ++e) d8[e] += bf2f(u[e]);
    }
  }
#pragma unroll
  for (int e = 0; e < 8; ++e) d8[e] += __shfl_xor(d8[e], 16, 64);
#pragma unroll
  for (int e = 0; e < 8; ++e) d8[e] += __shfl_xor(d8[e], 32, 64);

  const int r1 = __shfl(myidx, 25, 64);
  if (sub == 0) {
#pragma unroll
    for (int e = 0; e < 8; ++e) gD[j][c8 * 8 + e] = fmaxf(d8[e] * 0.04f, 0.f);
    const float4 raw = *(const float4*)(Y0 + r1 * 128 + c8 * 8);
    const unsigned short* u = (const unsigned short*)&raw;
#pragma unroll
    for (int e = 0; e < 8; ++e) gB[j][c8 * 8 + e] = bf2f(u[e]);
  } else if (sub == 1) {
    const float4 raw = *(const float4*)(X0 + r1 * 128 + c8 * 8);
    const unsigned short* u = (const unsigned short*)&raw;
#pragma unroll
    for (int e = 0; e < 8; ++e) gC[j][c8 * 8 + e] = fmaxf(bf2f(u[e]), 0.f);
  }
  __syncthreads();

  if (t < 512) {
    const int q = t >> 7, c = t & 127;
    float v;
    if (q == 0) {
      v = fmaxf(bf2f(X0[n0 * 128 + c]), 0.f);
    } else {
      const float* g = (q == 1) ? &gB[0][0] : (q == 2) ? &gC[0][0] : &gD[0][0];
      float s = 0.f;
#pragma unroll
      for (int jj = 0; jj < 10; ++jj) s += g[jj * 128 + c];
      v = s * 0.1f;
      if (q == 1) v = fmaxf(v, 0.f);
    }
    H[i * 512 + t] = v;
  }
}

__device__ __forceinline__ float softplusf(float x) {
  return fmaxf(x, 0.f) + log1pf(expf(-fabsf(x)));
}

// NT[d][c] = R[neg_idx[c]][d] — dense transposed neg embeddings (0.5 MB).
__global__ __launch_bounds__(256) void k_prep(
    const float* __restrict__ R, const int* __restrict__ neg_idx,
    float* __restrict__ NT) {
  const int idx = blockIdx.x * 256 + threadIdx.x;   // 128 blocks: 32768 f4 jobs
  const int c = idx & 511;
  const int d4 = idx >> 9;                          // 0..63
  const float4 v = *(const float4*)&R[neg_idx[c] * 256 + d4 * 4];
#pragma unroll
  for (int i2 = 0; i2 < 4; ++i2)
    NT[(d4 * 4 + i2) * 512 + c] = ((const float*)&v)[i2];
}

// neg_aff v6 = v5 + (1) DE-PHASED K-sweep: each block starts its d4 loop at
// a per-block rotation (wrapping), so concurrently-resident blocks on one
// XCD no longer request the SAME NT lines in lockstep (v5's 56us was
// same-line L2 serialization: effective latency ~2000cy, VALUBusy 14%,
// HBM 1%). (2) Col-split wave mapping: waves {0,1} own cols 0-63, waves
// {2,3} own cols 64-127 -> cross-wave B duplication 4x -> 2x (L2 traffic
// 262 -> 131 MB).
// Tie semantics: within a block ALL chains (neg accs and aff) use the SAME
// rotated d-sequence, fmaf step by step on the same staged bits -> dot(S,P)
// bitwise == dot(S,N) whenever pos_idx==neg_idx (stable positive-last rank:
// rank = #(neg >= aff)). Finalize fused via done-counter (target 511).
__global__ __launch_bounds__(256) void k_neg(
    const float* __restrict__ O, const float* __restrict__ NT,
    const int* __restrict__ src_idx, const int* __restrict__ pos_idx,
    float* __restrict__ out_src, int* __restrict__ rank,
    float* __restrict__ spPos, float* __restrict__ spNeg,
    int* __restrict__ done) {
  __shared__ float SP[16 * 260];     // rows [0,8) src, [8,16) pos
  __shared__ float affL[8];
  __shared__ int cntL[8];
  __shared__ float wsum[8];
  __shared__ int lastDone;
  const int t = threadIdx.x;
  const int bid = blockIdx.x;
  const int rowBase = (bid >> 2) * 8;   // 128 row-tiles
  const int colBase = (bid & 3) * 128;  // 4 col-tiles
  const bool first = (colBase == 0);
  // distinct sweep-start for concurrently-resident blocks (same-XCD blocks
  // differ in bid>>3; cross-XCD same-slot blocks differ in bid&7)
  const int rot = ((bid >> 3) + ((bid & 7) << 3)) & 63;

  if (t < 8) cntL[t] = 0;

  // stage S (8 rows) + P (8 rows), full K=256, coalesced f4 gathers
  {
    const float4* __restrict__ s4 = (const float4*)O;
#pragma unroll
    for (int idx = t; idx < 16 * 64; idx += 256) {
      const int row = idx >> 6, c4 = idx & 63;
      const int rid = (row < 8) ? src_idx[rowBase + row]
                                : pos_idx[rowBase + row - 8];
      *(float4*)&SP[row * 260 + c4 * 4] = s4[rid * 64 + c4];
    }
  }
  if (first) {  // src_emb copy to d_out (8 rows x 64 float4)
    const float4* __restrict__ s4 = (const float4*)O;
    float4* __restrict__ d4o = (float4*)out_src;
#pragma unroll
    for (int idx = t; idx < 8 * 64; idx += 256) {
      const int rr = idx >> 6, c4 = idx & 63;
      d4o[(rowBase + rr) * 64 + c4] = s4[src_idx[rowBase + rr] * 64 + c4];
    }
  }
  __syncthreads();

  const int tc2 = t & 31;           // 32 col-pairs within the 64-col half
  const int chalf = t >> 7;         // 0/1: waves {0,1} cols 0-63, {2,3} 64-127
  const int rowg = (t >> 5) & 3;    // rows {rowg, rowg+4}
  const float* __restrict__ B = NT + colBase + chalf * 64 + 2 * tc2;
  const float* __restrict__ A0 = SP + rowg * 260;
  const float* __restrict__ A1 = SP + (rowg + 4) * 260;
  const float* __restrict__ SV = SP + t * 260;          // t<8 only
  const float* __restrict__ PV = SP + (8 + t) * 260;    // t<8 only

  float acc00 = 0.f, acc01 = 0.f, acc10 = 0.f, acc11 = 0.f, aff = 0.f;
#pragma unroll 4
  for (int g = 0; g < 64; ++g) {
    const int dd = ((g + rot) & 63) * 4;   // rotated sweep, wraps
    const float4 a0 = *(const float4*)&A0[dd];    // wave-broadcast LDS
    const float4 a1 = *(const float4*)&A1[dd];
    float2 b[4];
#pragma unroll
    for (int i2 = 0; i2 < 4; ++i2)
      b[i2] = *(const float2*)&B[(dd + i2) * 512]; // 256B contiguous / wave
    float4 sv, pv;
    if (t < 8) {
      sv = *(const float4*)&SV[dd];
      pv = *(const float4*)&PV[dd];
    }
#pragma unroll
    for (int i2 = 0; i2 < 4; ++i2) {
      const float va0 = ((const float*)&a0)[i2];
      const float va1 = ((const float*)&a1)[i2];
      acc00 = fmaf(va0, b[i2].x, acc00);
      acc01 = fmaf(va0, b[i2].y, acc01);
      acc10 = fmaf(va1, b[i2].x, acc10);
      acc11 = fmaf(va1, b[i2].y, acc11);
      if (t < 8)
        aff = fmaf(((const float*)&sv)[i2], ((const float*)&pv)[i2], aff);
    }
  }
  if (t < 8) affL[t] = aff;
  __syncthreads();

  // 32-lane-group reduce: group (t>>5) owns rows {rowg, rowg+4}, col-half chalf
  float sp = softplusf(acc00) + softplusf(acc01) +
             softplusf(acc10) + softplusf(acc11);
  const float av0 = affL[rowg], av1 = affL[rowg + 4];
  int c0 = ((acc00 >= av0) ? 1 : 0) + ((acc01 >= av0) ? 1 : 0);
  int c1 = ((acc10 >= av1) ? 1 : 0) + ((acc11 >= av1) ? 1 : 0);
#pragma unroll
  for (int off = 16; off > 0; off >>= 1) {
    sp += __shfl_down(sp, off, 32);
    c0 += __shfl_down(c0, off, 32);
    c1 += __shfl_down(c1, off, 32);
  }
  if ((t & 31) == 0) {               // 8 writers: (rowg, chalf)
    atomicAdd(&cntL[rowg], c0);
    atomicAdd(&cntL[rowg + 4], c1);
    wsum[t >> 5] = sp;
  }
  __syncthreads();
  if (t < 8) atomicAdd(&rank[rowBase + t], cntL[t]);
  if (t == 0)
    atomicAdd(spNeg, wsum[0] + wsum[1] + wsum[2] + wsum[3] +
                     wsum[4] + wsum[5] + wsum[6] + wsum[7]);
  if (first && t < 8) atomicAdd(spPos, softplusf(-affL[t]));

  // ---- fused finalize: last block computes mrr + loss ----
  __threadfence();
  __syncthreads();
  if (t == 0) lastDone = (atomicAdd(done, 1) == 511) ? 1 : 0;
  __syncthreads();
  if (lastDone) {
    float s = 0.f;
    for (int i = t; i < BATCH; i += 256) {
      const int rv = __hip_atomic_load(&rank[i], __ATOMIC_RELAXED,
                                       __HIP_MEMORY_SCOPE_AGENT);
      s += 1.f / (float)(rv + 1);
    }
#pragma unroll
    for (int off = 32; off > 0; off >>= 1) s += __shfl_down(s, off, 64);
    if ((t & 63) == 0) wsum[t >> 6] = s;
    __syncthreads();
    if (t == 0) {
      const float mrr = (wsum[0] + wsum[1] + wsum[2] + wsum[3]) * (1.f / 1024.f);
      const float p = __hip_atomic_load(spPos, __ATOMIC_RELAXED,
                                        __HIP_MEMORY_SCOPE_AGENT);
      const float n = __hip_atomic_load(spNeg, __ATOMIC_RELAXED,
                                        __HIP_MEMORY_SCOPE_AGENT);
      out_src[BATCH * 256]     = (p + n) * (1.f / 1024.f);
      out_src[BATCH * 256 + 1] = mrr;
    }
  }
}

extern "C" void kernel_launch(void* const* d_in, const int* in_sizes, int n_in,
                              void* d_out, int out_size, void* d_ws, size_t ws_size,
                              hipStream_t stream) {
  const float* feat   = (const float*)d_in[1];
  const int* src_idx  = (const int*)d_in[2];
  const int* pos_idx  = (const int*)d_in[3];
  const int* neg_idx  = (const int*)d_in[4];
  const int* nb0      = (const int*)d_in[5];
  const int* nb1      = (const int*)d_in[6];
  const int* nb2      = (const int*)d_in[7];
  const float* ws0    = (const float*)d_in[8];
  const float* wn0    = (const float*)d_in[9];
  const float* ws1    = (const float*)d_in[10];
  const float* wn1    = (const float*)d_in[11];

  float* wsf = (float*)d_ws;
  unsigned short* X0 = (unsigned short*)d_ws;       // bf16[393216]
  unsigned short* Y0 = X0 + 393216;                 // bf16[393216]
  float* H     = wsf + 393216;                      // 3072*512
  float* R     = wsf + 1966080;                     // 3072*256
  float* spPos = wsf + 2752512;
  float* spNeg = wsf + 2752513;
  int*   rank  = (int*)(wsf + 2752514);
  int*   done  = rank + 1024;
  float* NT    = wsf + 2753540;                     // float[256][512]
  float* out   = (float*)d_out;

  // X0 = bf16(feat@ws0), Y0 = bf16(feat@wn0); block 0 zeroes spPos/spNeg/rank/done
  k_mm<128, 128, 0, false, unsigned short><<<L0 / 6, 512, 0, stream>>>(
      feat, ws0, wn0, X0, 128, 393216, spPos, 1027);
  k_aggregate<<<L0, 640, 0, stream>>>(X0, Y0, nb0, nb1, nb2, H);
  // R[:, :128] = H[:, :256]@ws1 ; R[:, 128:] = H[:, 256:]@wn1 ; + L2-norm
  k_mm<256, 512, 256, true, float><<<L0 / 6, 512, 0, stream>>>(
      H, ws1, wn1, R, 256, 128, nullptr, 0);
  // NT = neg_emb^T dense (0.5 MB)
  k_prep<<<128, 256, 0, stream>>>(R, neg_idx, NT);
  // 512 blocks = 128 row-tiles x 4 col-tiles; finalize fused (done-counter)
  k_neg<<<512, 256, 0, stream>>>(
      R, NT, src_idx, pos_idx, out, rank, spPos, spNeg, done);
}

// Round 7
// 157.363 us; speedup vs baseline: 1.5190x; 1.1338x over previous
//
#include <hip/hip_runtime.h>
#include <math.h>

// Problem constants (from reference setup_inputs)
#define L0      3072
#define BATCH   1024
#define NNEG    512

// -------- workspace layout (float indices into d_ws) --------
// X0 : bf16[393216]            (feat @ w_self_0, bf16)
// Y0 : bf16[393216]            = X0 + 393216 elems
// H  : float @ 393216 (3072*512)   [A,B | C,D] layer-1 inputs
// R  : float @ 1966080 (3072*256)  layer-1 output, normalized
// spPosPart @ 2752512 (float[128]), spNegPart @ 2752640 (float[512]),
// rankPart @ 2753152 (int[4*1024]), NT @ 2757248 (float[256][512])

__device__ __forceinline__ float bf2f(unsigned short u) {
  return __uint_as_float(((unsigned)u) << 16);
}
__device__ __forceinline__ void store_out(float v, float* p) { *p = v; }
__device__ __forceinline__ void store_out(float v, unsigned short* p) {
  unsigned x = __float_as_uint(v);                 // f32 -> bf16 RNE
  *p = (unsigned short)((x + 0x7fff + ((x >> 16) & 1)) >> 16);
}

// Half-split matmul, 6 rows x 256 cols per 512-thread block. (unchanged, R2;
// zbuf zeroing duty removed — nothing needs zeroing anymore)
template<int K, int AW, int HOFF, bool NORM, typename OutT>
__global__ __launch_bounds__(512) void k_mm(
    const float* __restrict__ Ain,
    const float* __restrict__ W0, const float* __restrict__ W1,
    OutT* __restrict__ Out, const int ldo, const int outHalfOff) {
  __shared__ float AT[6 * AW];
  __shared__ float rs[8][3];
  const int t = threadIdx.x;
  const int base = blockIdx.x * 6;
  {
    const float4* __restrict__ src = (const float4*)(Ain + base * AW);
    float4* __restrict__ dst = (float4*)AT;
    for (int idx = t; idx < 6 * AW / 4; idx += 512) dst[idx] = src[idx];
  }
  __syncthreads();

  const int wave = t >> 6;
  const int half = wave >> 2;
  const int colg = (wave >> 1) & 1;
  const int rowg = wave & 1;
  const int rg = rowg * 3;
  const int col = colg * 64 + (t & 63);
  const float* __restrict__ W = (half ? W1 : W0) + col;
  const float* __restrict__ A0 = AT + rg * AW + half * HOFF;

  float acc[3] = {0.f, 0.f, 0.f};
#pragma unroll 4
  for (int d = 0; d < K; d += 4) {
    float4 a[3];
#pragma unroll
    for (int r = 0; r < 3; ++r) a[r] = *(const float4*)&A0[r * AW + d];
    float w[4];
#pragma unroll
    for (int i2 = 0; i2 < 4; ++i2) w[i2] = W[(d + i2) * 128];
#pragma unroll
    for (int i2 = 0; i2 < 4; ++i2)
#pragma unroll
      for (int r = 0; r < 3; ++r)
        acc[r] = fmaf(((const float*)&a[r])[i2], w[i2], acc[r]);
  }

  float scale[3] = {1.f, 1.f, 1.f};
  if (NORM) {
    float p[3];
#pragma unroll
    for (int r = 0; r < 3; ++r) p[r] = acc[r] * acc[r];
#pragma unroll
    for (int off = 32; off > 0; off >>= 1)
#pragma unroll
      for (int r = 0; r < 3; ++r) p[r] += __shfl_xor(p[r], off, 64);
    if ((t & 63) == 0) { rs[wave][0] = p[0]; rs[wave][1] = p[1]; rs[wave][2] = p[2]; }
    __syncthreads();
#pragma unroll
    for (int r = 0; r < 3; ++r) {
      const float s = rs[rowg][r] + rs[rowg + 2][r] + rs[rowg + 4][r] + rs[rowg + 6][r];
      scale[r] = rsqrtf(fmaxf(s, 1e-12f));
    }
  }
  OutT* __restrict__ O = Out + half * outHalfOff;
#pragma unroll
  for (int r = 0; r < 3; ++r)
    store_out(acc[r] * scale[r], &O[(base + rg + r) * ldo + col]);
}

// Fused layer-0 + layer-1 aggregation, bf16 gathers, ONE barrier. (unchanged, R2)
__global__ __launch_bounds__(640) void k_aggregate(
    const unsigned short* __restrict__ X0, const unsigned short* __restrict__ Y0,
    const int* __restrict__ nb0, const int* __restrict__ nb1,
    const int* __restrict__ nb2, float* __restrict__ H) {
  __shared__ float gB[10][128], gC[10][128], gD[10][128];
  const int i = blockIdx.x;
  const int t = threadIdx.x;
  const int n0 = nb0[i];
  const int j = t >> 6;
  const int lam = t & 63;
  const int r = i * 10 + j;
  int myidx = 0;
  if (lam < 25) myidx = nb2[r * 25 + lam];
  else if (lam == 25) myidx = nb1[r];
  const int c8 = lam & 15;
  const int sub = lam >> 4;

  float d8[8];
#pragma unroll
  for (int e = 0; e < 8; ++e) d8[e] = 0.f;
#pragma unroll
  for (int m = 0; m < 7; ++m) {
    const int k = sub + 4 * m;
    const int ridx = __shfl(myidx, k, 64);
    if (k < 25) {
      const float4 raw = *(const float4*)(Y0 + ridx * 128 + c8 * 8);
      const unsigned short* u = (const unsigned short*)&raw;
#pragma unroll
      for (int e = 0; e < 8; ++e) d8[e] += bf2f(u[e]);
    }
  }
#pragma unroll
  for (int e = 0; e < 8; ++e) d8[e] += __shfl_xor(d8[e], 16, 64);
#pragma unroll
  for (int e = 0; e < 8; ++e) d8[e] += __shfl_xor(d8[e], 32, 64);

  const int r1 = __shfl(myidx, 25, 64);
  if (sub == 0) {
#pragma unroll
    for (int e = 0; e < 8; ++e) gD[j][c8 * 8 + e] = fmaxf(d8[e] * 0.04f, 0.f);
    const float4 raw = *(const float4*)(Y0 + r1 * 128 + c8 * 8);
    const unsigned short* u = (const unsigned short*)&raw;
#pragma unroll
    for (int e = 0; e < 8; ++e) gB[j][c8 * 8 + e] = bf2f(u[e]);
  } else if (sub == 1) {
    const float4 raw = *(const float4*)(X0 + r1 * 128 + c8 * 8);
    const unsigned short* u = (const unsigned short*)&raw;
#pragma unroll
    for (int e = 0; e < 8; ++e) gC[j][c8 * 8 + e] = fmaxf(bf2f(u[e]), 0.f);
  }
  __syncthreads();

  if (t < 512) {
    const int q = t >> 7, c = t & 127;
    float v;
    if (q == 0) {
      v = fmaxf(bf2f(X0[n0 * 128 + c]), 0.f);
    } else {
      const float* g = (q == 1) ? &gB[0][0] : (q == 2) ? &gC[0][0] : &gD[0][0];
      float s = 0.f;
#pragma unroll
      for (int jj = 0; jj < 10; ++jj) s += g[jj * 128 + c];
      v = s * 0.1f;
      if (q == 1) v = fmaxf(v, 0.f);
    }
    H[i * 512 + t] = v;
  }
}

__device__ __forceinline__ float softplusf(float x) {
  return fmaxf(x, 0.f) + log1pf(expf(-fabsf(x)));
}

// NT[d][c] = R[neg_idx[c]][d] — dense transposed neg embeddings (0.5 MB).
__global__ __launch_bounds__(256) void k_prep(
    const float* __restrict__ R, const int* __restrict__ neg_idx,
    float* __restrict__ NT) {
  const int idx = blockIdx.x * 256 + threadIdx.x;   // 128 blocks: 32768 f4 jobs
  const int c = idx & 511;
  const int d4 = idx >> 9;                          // 0..63
  const float4 v = *(const float4*)&R[neg_idx[c] * 256 + d4 * 4];
#pragma unroll
  for (int i2 = 0; i2 < 4; ++i2)
    NT[(d4 * 4 + i2) * 512 + c] = ((const float*)&v)[i2];
}

// neg_aff v7 = v6 main loop + DE-ATOMICIZED tail. Five rounds showed every
// k_neg variant stuck at 40-56us regardless of occupancy/traffic/structure:
// the invariant was ~2000 device-scope same-line atomic RMWs (spPos 1024 +
// spNeg 512 + done 512, all on ONE cache line, issued in a burst when the
// lockstep blocks finish) serializing at the owning L2 slice. v7 removes
// EVERY global atomic: each block writes plain stores to disjoint slots
// (spNegPart[bid], spPosPart[rowTile], rankPart[colTile*1024+row]); a tiny
// k_finalize sums them. Every rankPart entry is written -> no zeroing pass.
// Tie semantics unchanged (rank counts computed identically; only the
// cross-block integer/float summation moves to k_finalize, now in a fixed
// deterministic order).
__global__ __launch_bounds__(256) void k_neg(
    const float* __restrict__ O, const float* __restrict__ NT,
    const int* __restrict__ src_idx, const int* __restrict__ pos_idx,
    float* __restrict__ out_src, int* __restrict__ rankPart,
    float* __restrict__ spPosPart, float* __restrict__ spNegPart) {
  __shared__ float SP[16 * 260];     // rows [0,8) src, [8,16) pos
  __shared__ float affL[8];
  __shared__ int cntL[8];
  __shared__ float wsum[8];
  const int t = threadIdx.x;
  const int bid = blockIdx.x;
  const int rowBase = (bid >> 2) * 8;   // 128 row-tiles
  const int colBase = (bid & 3) * 128;  // 4 col-tiles
  const bool first = (colBase == 0);
  // distinct sweep-start for concurrently-resident blocks
  const int rot = ((bid >> 3) + ((bid & 7) << 3)) & 63;

  if (t < 8) cntL[t] = 0;

  // stage S (8 rows) + P (8 rows), full K=256, coalesced f4 gathers
  {
    const float4* __restrict__ s4 = (const float4*)O;
#pragma unroll
    for (int idx = t; idx < 16 * 64; idx += 256) {
      const int row = idx >> 6, c4 = idx & 63;
      const int rid = (row < 8) ? src_idx[rowBase + row]
                                : pos_idx[rowBase + row - 8];
      *(float4*)&SP[row * 260 + c4 * 4] = s4[rid * 64 + c4];
    }
  }
  if (first) {  // src_emb copy to d_out (8 rows x 64 float4)
    const float4* __restrict__ s4 = (const float4*)O;
    float4* __restrict__ d4o = (float4*)out_src;
#pragma unroll
    for (int idx = t; idx < 8 * 64; idx += 256) {
      const int rr = idx >> 6, c4 = idx & 63;
      d4o[(rowBase + rr) * 64 + c4] = s4[src_idx[rowBase + rr] * 64 + c4];
    }
  }
  __syncthreads();

  const int tc2 = t & 31;           // 32 col-pairs within the 64-col half
  const int chalf = t >> 7;         // 0/1: waves {0,1} cols 0-63, {2,3} 64-127
  const int rowg = (t >> 5) & 3;    // rows {rowg, rowg+4}
  const float* __restrict__ B = NT + colBase + chalf * 64 + 2 * tc2;
  const float* __restrict__ A0 = SP + rowg * 260;
  const float* __restrict__ A1 = SP + (rowg + 4) * 260;
  const float* __restrict__ SV = SP + t * 260;          // t<8 only
  const float* __restrict__ PV = SP + (8 + t) * 260;    // t<8 only

  float acc00 = 0.f, acc01 = 0.f, acc10 = 0.f, acc11 = 0.f, aff = 0.f;
#pragma unroll 4
  for (int g = 0; g < 64; ++g) {
    const int dd = ((g + rot) & 63) * 4;   // rotated sweep, wraps
    const float4 a0 = *(const float4*)&A0[dd];    // wave-broadcast LDS
    const float4 a1 = *(const float4*)&A1[dd];
    float2 b[4];
#pragma unroll
    for (int i2 = 0; i2 < 4; ++i2)
      b[i2] = *(const float2*)&B[(dd + i2) * 512]; // 256B contiguous / wave
    float4 sv, pv;
    if (t < 8) {
      sv = *(const float4*)&SV[dd];
      pv = *(const float4*)&PV[dd];
    }
#pragma unroll
    for (int i2 = 0; i2 < 4; ++i2) {
      const float va0 = ((const float*)&a0)[i2];
      const float va1 = ((const float*)&a1)[i2];
      acc00 = fmaf(va0, b[i2].x, acc00);
      acc01 = fmaf(va0, b[i2].y, acc01);
      acc10 = fmaf(va1, b[i2].x, acc10);
      acc11 = fmaf(va1, b[i2].y, acc11);
      if (t < 8)
        aff = fmaf(((const float*)&sv)[i2], ((const float*)&pv)[i2], aff);
    }
  }
  if (t < 8) affL[t] = aff;
  __syncthreads();

  // 32-lane-group reduce: group (t>>5) owns rows {rowg, rowg+4}, col-half chalf
  float sp = softplusf(acc00) + softplusf(acc01) +
             softplusf(acc10) + softplusf(acc11);
  const float av0 = affL[rowg], av1 = affL[rowg + 4];
  int c0 = ((acc00 >= av0) ? 1 : 0) + ((acc01 >= av0) ? 1 : 0);
  int c1 = ((acc10 >= av1) ? 1 : 0) + ((acc11 >= av1) ? 1 : 0);
#pragma unroll
  for (int off = 16; off > 0; off >>= 1) {
    sp += __shfl_down(sp, off, 32);
    c0 += __shfl_down(c0, off, 32);
    c1 += __shfl_down(c1, off, 32);
  }
  if ((t & 31) == 0) {               // 8 writers: (rowg, chalf); LDS atomics only
    atomicAdd(&cntL[rowg], c0);
    atomicAdd(&cntL[rowg + 4], c1);
    wsum[t >> 5] = sp;
  }
  __syncthreads();

  // ---- plain-store partials: ZERO global atomics ----
  if (t < 8) rankPart[(bid & 3) * 1024 + rowBase + t] = cntL[t];
  if (t == 0)
    spNegPart[bid] = wsum[0] + wsum[1] + wsum[2] + wsum[3] +
                     wsum[4] + wsum[5] + wsum[6] + wsum[7];
  if (first && t == 0) {
    float ps = 0.f;
#pragma unroll
    for (int r = 0; r < 8; ++r) ps += softplusf(-affL[r]);  // ascending, determ.
    spPosPart[bid >> 2] = ps;
  }
}

// mrr + loss from partials. 1 block.
__global__ __launch_bounds__(256) void k_finalize(
    const int* __restrict__ rankPart, const float* __restrict__ spPosPart,
    const float* __restrict__ spNegPart, float* __restrict__ out) {
  __shared__ float wa[4], wb[4];
  const int t = threadIdx.x;
  float s = 0.f;
  for (int i = t; i < BATCH; i += 256) {
    const int rv = rankPart[i] + rankPart[1024 + i] +
                   rankPart[2048 + i] + rankPart[3072 + i];
    s += 1.f / (float)(rv + 1);
  }
  float l = 0.f;
  for (int i = t; i < NNEG; i += 256) l += spNegPart[i];
  if (t < 128) l += spPosPart[t];
#pragma unroll
  for (int off = 32; off > 0; off >>= 1) {
    s += __shfl_down(s, off, 64);
    l += __shfl_down(l, off, 64);
  }
  if ((t & 63) == 0) { wa[t >> 6] = s; wb[t >> 6] = l; }
  __syncthreads();
  if (t == 0) {
    out[BATCH * 256]     = (wb[0] + wb[1] + wb[2] + wb[3]) * (1.f / 1024.f);
    out[BATCH * 256 + 1] = (wa[0] + wa[1] + wa[2] + wa[3]) * (1.f / 1024.f);
  }
}

extern "C" void kernel_launch(void* const* d_in, const int* in_sizes, int n_in,
                              void* d_out, int out_size, void* d_ws, size_t ws_size,
                              hipStream_t stream) {
  const float* feat   = (const float*)d_in[1];
  const int* src_idx  = (const int*)d_in[2];
  const int* pos_idx  = (const int*)d_in[3];
  const int* neg_idx  = (const int*)d_in[4];
  const int* nb0      = (const int*)d_in[5];
  const int* nb1      = (const int*)d_in[6];
  const int* nb2      = (const int*)d_in[7];
  const float* ws0    = (const float*)d_in[8];
  const float* wn0    = (const float*)d_in[9];
  const float* ws1    = (const float*)d_in[10];
  const float* wn1    = (const float*)d_in[11];

  float* wsf = (float*)d_ws;
  unsigned short* X0 = (unsigned short*)d_ws;       // bf16[393216]
  unsigned short* Y0 = X0 + 393216;                 // bf16[393216]
  float* H       = wsf + 393216;                    // 3072*512
  float* R       = wsf + 1966080;                   // 3072*256
  float* spPosP  = wsf + 2752512;                   // float[128]
  float* spNegP  = wsf + 2752640;                   // float[512]
  int*   rankP   = (int*)(wsf + 2753152);           // int[4*1024]
  float* NT      = wsf + 2757248;                   // float[256][512]
  float* out     = (float*)d_out;

  // X0 = bf16(feat@ws0), Y0 = bf16(feat@wn0)
  k_mm<128, 128, 0, false, unsigned short><<<L0 / 6, 512, 0, stream>>>(
      feat, ws0, wn0, X0, 128, 393216);
  k_aggregate<<<L0, 640, 0, stream>>>(X0, Y0, nb0, nb1, nb2, H);
  // R[:, :128] = H[:, :256]@ws1 ; R[:, 128:] = H[:, 256:]@wn1 ; + L2-norm
  k_mm<256, 512, 256, true, float><<<L0 / 6, 512, 0, stream>>>(
      H, ws1, wn1, R, 256, 128);
  // NT = neg_emb^T dense (0.5 MB)
  k_prep<<<128, 256, 0, stream>>>(R, neg_idx, NT);
  // 512 blocks = 128 row-tiles x 4 col-tiles; NO global atomics
  k_neg<<<512, 256, 0, stream>>>(
      R, NT, src_idx, pos_idx, out, rankP, spPosP, spNegP);
  k_finalize<<<1, 256, 0, stream>>>(rankP, spPosP, spNegP, out);
}